// Round 4
// baseline (290.253 us; speedup 1.0000x reference)
//
#include <hip/hip_runtime.h>
#include <cstddef>

#define H_   512
#define W_   512
#define NIMG 96            // 32 batch * 3 channels
#define PD_  16            // pad = KS/2
#define TY   64            // output rows per band
#define NROWS (TY + 31)    // 95 padded rows per band

// one DPP scan step: x += dpp_shifted(x); bound_ctrl=1 -> out-of-range reads 0
template <int CTRL, int RMASK>
__device__ __forceinline__ float dpp_add(float x) {
    int t = __builtin_amdgcn_update_dpp(0, __float_as_int(x), CTRL, RMASK, 0xf, true);
    return x + __int_as_float(t);
}

// wave64 inclusive prefix sum, pure VALU (6 dpp-adds)
__device__ __forceinline__ float wave_incl_scan(float x) {
    x = dpp_add<0x111, 0xf>(x);   // row_shr:1
    x = dpp_add<0x112, 0xf>(x);   // row_shr:2
    x = dpp_add<0x114, 0xf>(x);   // row_shr:4
    x = dpp_add<0x118, 0xf>(x);   // row_shr:8
    x = dpp_add<0x142, 0xa>(x);   // row_bcast:15 -> rows 1,3
    x = dpp_add<0x143, 0xc>(x);   // row_bcast:31 -> rows 2,3
    return x;
}

__device__ __forceinline__ float bcast63(float x) {
    return __int_as_float(__builtin_amdgcn_readlane(__float_as_int(x), 63));
}

// Each wave owns 128 output cols (2 per lane: j=2L even, j=2L+1 odd).
// Horizontal 32-window via pair prefix scan over 159 padded cols
// (main 128 in 64 lane-pairs + tail 31 in lanes 0..15's pairs).
// Vertical 32-window via 4 rolling accumulators; the LEAVING row's h is
// RECOMPUTED (L2 hit) instead of kept in a 32-deep register ring -> the
// whole loop stays rolled (~2.5 KB code, I$-resident) and VGPRs stay low.
// No LDS, no barriers. All shuffles executed under full exec (R2 lesson).
__global__ void __launch_bounds__(256, 4)
localnorm_kernel(const float* __restrict__ xin, float* __restrict__ out)
{
    const int lane = threadIdx.x & 63;
    const int wv   = threadIdx.x >> 6;
    const int c0   = wv * 128;          // wave's first output col (grid.x == 1)
    const int row0 = blockIdx.y * TY;
    const int img  = blockIdx.z;

    const float* __restrict__ src = xin + (size_t)img * (H_ * W_);
    float* __restrict__ dst = out + (size_t)img * (H_ * W_);

    // reflected column element-offsets (row-invariant)
    auto refl = [](int c) { return (c < 0) ? -c : ((c > W_ - 1) ? 2 * (W_ - 1) - c : c); };
    const int pc0 = c0 - PD_;
    const int om0 = refl(pc0 + 2 * lane);          // main pair: padded cols 2L, 2L+1
    const int om1 = refl(pc0 + 2 * lane + 1);
    const int ot0 = refl(pc0 + 128 + 2 * lane);    // tail pair: padded cols 128+2L, 129+2L
    const int ot1 = refl(pc0 + 128 + 2 * lane + 1);
    const bool tlane = lane < 16;                  // tail active lanes (covers cols 128..159)

    float vge = 0.f, vgo = 0.f, vqe = 0.f, vqo = 0.f;   // vertical rolling sums

    // h window sums for padded row p: hge/hqe (even col j=2L), hgo/hqo (odd)
    auto Hrow = [&](int p, float& hge, float& hgo, float& hqe, float& hqo) {
        int r = row0 + p - PD_;                     // wave-uniform row reflect
        r = (r < 0) ? -r : ((r > H_ - 1) ? 2 * (H_ - 1) - r : r);
        const float* __restrict__ rp = src + (size_t)r * W_;
        float a = rp[om0];
        float b = rp[om1];
        float ta = 0.f, tb = 0.f;
        if (tlane) { ta = rp[ot0]; tb = rp[ot1]; }  // exec-masked; others stay 0
        float qa = a * a, qb = b * b, qta = ta * ta, qtb = tb * tb;

        // pair scans: P(L) = S[2L+1] (main), T(M) = sum of tail pairs 0..M
        float Pg = wave_incl_scan(a + b);
        float Pq = wave_incl_scan(qa + qb);
        float Tg = wave_incl_scan(ta + tb);
        float Tq = wave_incl_scan(qta + qtb);
        float S127g = bcast63(Pg), S127q = bcast63(Pq);   // S[127] = main total
        float Eg = Pg - b,  Eq = Pq - qb;                 // S[2L]
        float TEg = Tg - tb, TEq = Tq - qtb;              // tail sums excl. last elem

        // all shuffles unconditional (full exec), selected afterwards
        float Pg15  = __shfl_down(Pg, 15),  Pq15  = __shfl_down(Pq, 15);
        float Eg16  = __shfl_down(Eg, 16),  Eq16  = __shfl_down(Eq, 16);
        float Tg49  = __shfl_up(Tg, 49),    Tq49  = __shfl_up(Tq, 49);
        float TEg48 = __shfl_up(TEg, 48),   TEq48 = __shfl_up(TEq, 48);

        // S[2L+31]: odd idx -> P(L+15) or S127 + T(L-49)
        float upEg = (lane <= 48) ? Pg15 : S127g + Tg49;
        float upEq = (lane <= 48) ? Pq15 : S127q + Tq49;
        // S[2L+32]: even idx -> E(L+16) or S127 + TE(L-48)
        float upOg = (lane <= 47) ? Eg16 : S127g + TEg48;
        float upOq = (lane <= 47) ? Eq16 : S127q + TEq48;

        // hsum[j] = S[j+31] - S[j-1];  S[2L-1] = P(L)-pair(L),  S[2L] = E(L)
        hge = upEg - (Pg - (a + b));
        hqe = upEq - (Pq - (qa + qb));
        hgo = upOg - Eg;
        hqo = upOq - Eq;
    };

    // prologue: padded rows 0..30
    for (int p = 0; p < 31; ++p) {
        float hge, hgo, hqe, hqo;
        Hrow(p, hge, hgo, hqe, hqo);
        vge += hge; vgo += hgo; vqe += hqe; vqo += hqo;
    }

    auto emit = [&](int i) {
        int ri = row0 + i;
        const float2 xv = *(const float2*)(src + (size_t)ri * W_ + c0 + 2 * lane);
        float mge = vge * (1.f / 1024.f), mqe = vqe * (1.f / 1024.f);
        float mgo = vgo * (1.f / 1024.f), mqo = vqo * (1.f / 1024.f);
        float sde = sqrtf(fabsf(mqe - mge * mge)) + 1e-10f;
        float sdo = sqrtf(fabsf(mqo - mgo * mgo)) + 1e-10f;
        float re = fminf(fmaxf(__fdividef(xv.x - mge, sde), -6.f), 6.f);
        float ro = fminf(fmaxf(__fdividef(xv.y - mgo, sdo), -6.f), 6.f);
        *(float2*)(dst + (size_t)ri * W_ + c0 + 2 * lane) = make_float2(re, ro);
    };

    // i = 0: add entering row 31, emit, no subtract yet
    {
        float hge, hgo, hqe, hqo;
        Hrow(31, hge, hgo, hqe, hqo);
        vge += hge; vgo += hgo; vqe += hqe; vqo += hqo;
        emit(0);
    }
    // main: i = 1..63  (rolled; ~2 Hrow + epilogue per iteration)
    for (int i = 1; i < TY; ++i) {
        float hge, hgo, hqe, hqo;
        Hrow(i + 31, hge, hgo, hqe, hqo);          // entering padded row
        float sge, sgo, sqe, sqo;
        Hrow(i - 1, sge, sgo, sqe, sqo);           // leaving row, recomputed (L2 hit)
        vge += hge - sge; vgo += hgo - sgo;
        vqe += hqe - sqe; vqo += hqo - sqo;
        emit(i);
    }
}

extern "C" void kernel_launch(void* const* d_in, const int* in_sizes, int n_in,
                              void* d_out, int out_size, void* d_ws, size_t ws_size,
                              hipStream_t stream) {
    (void)in_sizes; (void)n_in; (void)d_ws; (void)ws_size; (void)out_size;
    const float* x = (const float*)d_in[0];
    float* o = (float*)d_out;
    dim3 grid(1, H_ / TY, NIMG);    // 1 x 8 x 96 = 768 blocks
    localnorm_kernel<<<grid, dim3(256), 0, stream>>>(x, o);
}